// Round 9
// baseline (337.743 us; speedup 1.0000x reference)
//
#include <hip/hip_runtime.h>

#define BATCH 64
#define HH 512
#define WW 512
#define TH 32                  // output rows per strip
#define KS 11
#define PADK 5
#define NIN (TH + 2 * PADK)    // 42 valid input rows per strip (44 slots, 2 cut)
#define NF4 262                // float4 slots/row: 3 pad + 256 px-pairs + 3 pad
#define NPIX (64.0 * 512.0 * 512.0)

// 256 threads; thread t owns output cols 2t,2t+1 of a TH=32-row strip.
// LDS stages float4{a0,b0,a1,b1} per px PAIR (8 B/px): the 12-px union
// window of cols 2t,2t+1 is pair-aligned -> 7 b128 reads serve BOTH
// columns (3.5 reads/col vs round-7's 11) and all Gaussian weights are
// compile-time LITERALS (round 8's per-thread parity weights triggered
// rematerialization codegen: VALU +40%, VGPR starved to 68 -> 3-block
// tail). q=a^2+b^2, p=ab recomputed at read time.
// Fixes carried (each HW-proven): named-scalar ring (r3/r7: WRITE_SIZE
// 53MB->32B), 4-row dbuf chunks + ONE barrier/chunk (r6: barriers are
// live-range fences), 33.5 KB LDS + 256-thr blocks -> 4 resident = 4
// work blocks/CU (r3/r8 tail killed), launch_bounds cap 128 with ~30
// regs of measured headroom (r3: this ring+staging = 92 VGPR; r4's
// spill was live~145 vs cap 128).
__global__ void __launch_bounds__(256, 4) ssim_main_kernel(
    const float* __restrict__ img1, const float* __restrict__ img2,
    double* __restrict__ accum) {
  constexpr float GA[KS] = {
      0.00102838f, 0.00759884f, 0.03600087f, 0.10936069f, 0.21300553f,
      0.26601172f, 0.21300553f, 0.10936069f, 0.03600087f, 0.00759884f,
      0.00102838f};
  const float C1v = 1e-4f, C2v = 9e-4f;

  const int t  = threadIdx.x;          // 0..255
  const int r0 = blockIdx.x * TH;      // first output row of strip
  const int b  = blockIdx.y;           // batch index

  const float2* __restrict__ pp1 =
      reinterpret_cast<const float2*>(img1 + (size_t)b * HH * WW);
  const float2* __restrict__ pp2 =
      reinterpret_cast<const float2*>(img2 + (size_t)b * HH * WW);

  // Slot s holds px pair (2(s-3), 2(s-3)+1) as {a0,b0,a1,b1}.
  __shared__ float4 s4[2][4][NF4];
  __shared__ float wsum[4];

  // Zero horizontal pads of both buffers once (slots 0..2 and 259..261).
  if (t < 6) {
    const int idx = (t < 3) ? t : (256 + t);
#pragma unroll
    for (int bi = 0; bi < 2; ++bi)
#pragma unroll
      for (int r = 0; r < 4; ++r) s4[bi][r][idx] = make_float4(0.f, 0.f, 0.f, 0.f);
  }

  // Ring: 88 named scalars; slot s holds h-conv of input row rc, rc%11==s;
  // x* = col 2t, y* = col 2t+1.
#define DECLR(s) float xA##s = 0.f, xB##s = 0.f, xQ##s = 0.f, xP##s = 0.f, \
                       yA##s = 0.f, yB##s = 0.f, yQ##s = 0.f, yP##s = 0.f;
  DECLR(0) DECLR(1) DECLR(2) DECLR(3) DECLR(4) DECLR(5)
  DECLR(6) DECLR(7) DECLR(8) DECLR(9) DECLR(10)

  float2 ta0, ta1, ta2, ta3, tb0, tb1, tb2, tb3;  // prefetch regs (own pair)
  float local = 0.f;

  // Load chunk k_ rows into named regs (rows >= NIN constexpr-cut; row
  // validity is block-uniform).
#define LD1(k_, j_)                                                     \
  {                                                                     \
    constexpr int rc_ = 4 * (k_) + (j_);                                \
    ta##j_ = make_float2(0.f, 0.f); tb##j_ = make_float2(0.f, 0.f);     \
    if constexpr (rc_ < NIN) {                                          \
      const int rr_ = r0 - PADK + rc_;                                  \
      if ((unsigned)rr_ < HH) {                                         \
        const int off_ = rr_ * (WW / 2) + t;                            \
        ta##j_ = pp1[off_];                                             \
        tb##j_ = pp2[off_];                                             \
      }                                                                 \
    }                                                                   \
  }
#define LOADC(k_) { LD1(k_, 0) LD1(k_, 1) LD1(k_, 2) LD1(k_, 3) }

  // Stage chunk k_ into buffer k_&1: one packed b128 write per row at
  // lane-consecutive slot t+3 (uniform bank coverage, r7-proven class).
#define WR1(k_, j_)                                                     \
  {                                                                     \
    constexpr int rc_ = 4 * (k_) + (j_);                                \
    if constexpr (rc_ < NIN)                                            \
      s4[(k_) & 1][j_][t + 3] =                                         \
          make_float4(ta##j_.x, tb##j_.x, ta##j_.y, tb##j_.y);          \
  }
#define WRITEC(k_) { WR1(k_, 0) WR1(k_, 1) WR1(k_, 2) WR1(k_, 3) }

  // Horizontal conv of LDS row j_ of buffer bb_ -> ring slot S. 7 b128
  // reads (slots t..t+6 = px 2t-6..2t+7); px rel. to col-2t window start
  // (px 2t-5): j0=2kk-1 (v.x,v.y), j1=2kk (v.z,v.w). Col 2t taps GA[j],
  // col 2t+1 taps GA[j-1]; out-of-window px constexpr-guarded.
  // (Verified numerically in rounds 2/3.)
#define HBODY(bb_, j_, S)                                                     \
  {                                                                           \
    float h0a = 0.f, h0b = 0.f, h0q = 0.f, h0p = 0.f;                         \
    float h1a = 0.f, h1b = 0.f, h1q = 0.f, h1p = 0.f;                         \
    _Pragma("unroll")                                                         \
    for (int kk = 0; kk < 7; ++kk) {                                          \
      const float4 v = s4[bb_][j_][t + kk];                                   \
      if (kk >= 1) { /* px j0 = 2kk-1 : a=v.x b=v.y */                        \
        const float qv_ = fmaf(v.x, v.x, v.y * v.y);                          \
        const float pv_ = v.x * v.y;                                          \
        if (kk <= 5) {                                                        \
          const float w_ = GA[2 * kk - 1];                                    \
          h0a = fmaf(w_, v.x, h0a); h0b = fmaf(w_, v.y, h0b);                 \
          h0q = fmaf(w_, qv_, h0q); h0p = fmaf(w_, pv_, h0p);                 \
        }                                                                     \
        {                                                                     \
          const float w_ = GA[2 * kk - 2];                                    \
          h1a = fmaf(w_, v.x, h1a); h1b = fmaf(w_, v.y, h1b);                 \
          h1q = fmaf(w_, qv_, h1q); h1p = fmaf(w_, pv_, h1p);                 \
        }                                                                     \
      }                                                                       \
      if (kk <= 5) { /* px j1 = 2kk : a=v.z b=v.w */                          \
        const float qv_ = fmaf(v.z, v.z, v.w * v.w);                          \
        const float pv_ = v.z * v.w;                                          \
        {                                                                     \
          const float w_ = GA[2 * kk];                                        \
          h0a = fmaf(w_, v.z, h0a); h0b = fmaf(w_, v.w, h0b);                 \
          h0q = fmaf(w_, qv_, h0q); h0p = fmaf(w_, pv_, h0p);                 \
        }                                                                     \
        if (kk >= 1) {                                                        \
          const float w_ = GA[2 * kk - 1];                                    \
          h1a = fmaf(w_, v.z, h1a); h1b = fmaf(w_, v.w, h1b);                 \
          h1q = fmaf(w_, qv_, h1q); h1p = fmaf(w_, pv_, h1p);                 \
        }                                                                     \
      }                                                                       \
    }                                                                         \
    xA##S = h0a; xB##S = h0b; xQ##S = h0q; xP##S = h0p;                       \
    yA##S = h1a; yB##S = h1b; yQ##S = h1q; yP##S = h1p;                       \
  }

  // Vertical conv: explicit rotation, slot names literal.
#define VC(P, s0,s1,s2v,s3,s4v,s5,s6v,s7,s8,s9,s10)                     \
  fmaf(GA[10], P##s10, fmaf(GA[9], P##s9, fmaf(GA[8], P##s8,            \
  fmaf(GA[7], P##s7, fmaf(GA[6], P##s6v, fmaf(GA[5], P##s5,             \
  fmaf(GA[4], P##s4v, fmaf(GA[3], P##s3, fmaf(GA[2], P##s2v,            \
  fmaf(GA[1], P##s1, GA[0] * P##s0))))))))))

#define SSIMACC                                                         \
  {                                                                     \
    const float m1s = m1 * m1, m2s = m2 * m2, m12 = m1 * m2;            \
    const float s12 = mp - m12;                                         \
    const float sqq = mq - m1s - m2s;                                   \
    const float num = fmaf(2.f, m12, C1v) * fmaf(2.f, s12, C2v);        \
    const float den = (m1s + m2s + C1v) * (sqq + C2v);                  \
    local = fmaf(num, __builtin_amdgcn_rcpf(den), local);               \
  }

#define VOUTBODY(s0,s1,s2v,s3,s4v,s5,s6v,s7,s8,s9,s10)                  \
  {                                                                     \
    {                                                                   \
      const float m1 = VC(xA, s0,s1,s2v,s3,s4v,s5,s6v,s7,s8,s9,s10);    \
      const float m2 = VC(xB, s0,s1,s2v,s3,s4v,s5,s6v,s7,s8,s9,s10);    \
      const float mq = VC(xQ, s0,s1,s2v,s3,s4v,s5,s6v,s7,s8,s9,s10);    \
      const float mp = VC(xP, s0,s1,s2v,s3,s4v,s5,s6v,s7,s8,s9,s10);    \
      SSIMACC                                                           \
    }                                                                   \
    {                                                                   \
      const float m1 = VC(yA, s0,s1,s2v,s3,s4v,s5,s6v,s7,s8,s9,s10);    \
      const float m2 = VC(yB, s0,s1,s2v,s3,s4v,s5,s6v,s7,s8,s9,s10);    \
      const float mq = VC(yQ, s0,s1,s2v,s3,s4v,s5,s6v,s7,s8,s9,s10);    \
      const float mp = VC(yP, s0,s1,s2v,s3,s4v,s5,s6v,s7,s8,s9,s10);    \
      SSIMACC                                                           \
    }                                                                   \
  }

#define ROT0  0,1,2,3,4,5,6,7,8,9,10
#define ROT1  1,2,3,4,5,6,7,8,9,10,0
#define ROT2  2,3,4,5,6,7,8,9,10,0,1
#define ROT3  3,4,5,6,7,8,9,10,0,1,2
#define ROT4  4,5,6,7,8,9,10,0,1,2,3
#define ROT5  5,6,7,8,9,10,0,1,2,3,4
#define ROT6  6,7,8,9,10,0,1,2,3,4,5
#define ROT7  7,8,9,10,0,1,2,3,4,5,6
#define ROT8  8,9,10,0,1,2,3,4,5,6,7
#define ROT9  9,10,0,1,2,3,4,5,6,7,8
#define ROT10 10,0,1,2,3,4,5,6,7,8,9
#define VOUTE(...) VOUTBODY(__VA_ARGS__)

#define ROWH(bb_, j_, S)      { HBODY(bb_, j_, S) }
#define ROWO(bb_, j_, S, R_)  { HBODY(bb_, j_, S) VOUTE(R_) }

  // Prologue: prefetch chunk 0.
  LOADC(0)

  // Per chunk ii (buf = ii&1): write staged regs; ONE barrier; prefetch
  // chunk ii+1 (latency hides under this chunk's compute); compute the
  // 4 rows. rc = 4*ii+j; ring slot S = rc%11; output row rc-10 emitted
  // when rc >= 10 using rotation start (rc+1)%11.
  // ii=0: rc 0-3
  WRITEC(0) __syncthreads(); LOADC(1)
  ROWH(0,0,0) ROWH(0,1,1) ROWH(0,2,2) ROWH(0,3,3)
  // ii=1: rc 4-7
  WRITEC(1) __syncthreads(); LOADC(2)
  ROWH(1,0,4) ROWH(1,1,5) ROWH(1,2,6) ROWH(1,3,7)
  // ii=2: rc 8-11 (rc10,11 -> output rows 0,1)
  WRITEC(2) __syncthreads(); LOADC(3)
  ROWH(0,0,8) ROWH(0,1,9)
  ROWO(0,2,10, ROT0) ROWO(0,3,0, ROT1)
  // ii=3: rc 12-15
  WRITEC(3) __syncthreads(); LOADC(4)
  ROWO(1,0,1, ROT2) ROWO(1,1,2, ROT3) ROWO(1,2,3, ROT4) ROWO(1,3,4, ROT5)
  // ii=4: rc 16-19
  WRITEC(4) __syncthreads(); LOADC(5)
  ROWO(0,0,5, ROT6) ROWO(0,1,6, ROT7) ROWO(0,2,7, ROT8) ROWO(0,3,8, ROT9)
  // ii=5: rc 20-23
  WRITEC(5) __syncthreads(); LOADC(6)
  ROWO(1,0,9, ROT10) ROWO(1,1,10, ROT0) ROWO(1,2,0, ROT1) ROWO(1,3,1, ROT2)
  // ii=6: rc 24-27
  WRITEC(6) __syncthreads(); LOADC(7)
  ROWO(0,0,2, ROT3) ROWO(0,1,3, ROT4) ROWO(0,2,4, ROT5) ROWO(0,3,5, ROT6)
  // ii=7: rc 28-31
  WRITEC(7) __syncthreads(); LOADC(8)
  ROWO(1,0,6, ROT7) ROWO(1,1,7, ROT8) ROWO(1,2,8, ROT9) ROWO(1,3,9, ROT10)
  // ii=8: rc 32-35
  WRITEC(8) __syncthreads(); LOADC(9)
  ROWO(0,0,10, ROT0) ROWO(0,1,0, ROT1) ROWO(0,2,1, ROT2) ROWO(0,3,2, ROT3)
  // ii=9: rc 36-39
  WRITEC(9) __syncthreads(); LOADC(10)
  ROWO(1,0,3, ROT4) ROWO(1,1,4, ROT5) ROWO(1,2,5, ROT6) ROWO(1,3,6, ROT7)
  // ii=10: rc 40,41 (output rows 30,31; rc 42,43 constexpr-cut)
  WRITEC(10) __syncthreads();
  ROWO(0,0,7, ROT8) ROWO(0,1,8, ROT9)

  // Block reduction: wave64 shuffle -> LDS -> one double atomic per block.
#pragma unroll
  for (int off = 32; off > 0; off >>= 1) local += __shfl_down(local, off, 64);
  const int wave = t >> 6;
  const int lane = t & 63;
  if (lane == 0) wsum[wave] = local;
  __syncthreads();
  if (t == 0) {
    float s = wsum[0] + wsum[1] + wsum[2] + wsum[3];
    atomicAdd(accum, (double)s);
  }
}

__global__ void ssim_final_kernel(const double* __restrict__ accum,
                                  float* __restrict__ out) {
  out[0] = 1.0f - (float)(accum[0] / NPIX);
}

extern "C" void kernel_launch(void* const* d_in, const int* in_sizes, int n_in,
                              void* d_out, int out_size, void* d_ws, size_t ws_size,
                              hipStream_t stream) {
  const float* img1 = (const float*)d_in[0];
  const float* img2 = (const float*)d_in[1];
  double* accum = (double*)d_ws;
  hipMemsetAsync(accum, 0, sizeof(double), stream);

  dim3 grid(HH / TH, BATCH);
  ssim_main_kernel<<<grid, 256, 0, stream>>>(img1, img2, accum);
  ssim_final_kernel<<<1, 1, 0, stream>>>(accum, (float*)d_out);
}

// Round 10
// 183.310 us; speedup vs baseline: 1.8425x; 1.8425x over previous
//
#include <hip/hip_runtime.h>

#define BATCH 64
#define HH 512
#define WW 512
#define TH 32                  // output rows per strip
#define KS 11
#define PADK 5
#define NIN (TH + 2 * PADK)    // 42 valid input rows per strip (44 slots, 2 cut)
#define NF4 262                // float4 slots/row: 3 pad + 256 px-pairs + 3 pad
#define NPIX (64.0 * 512.0 * 512.0)

// 512 threads, 1 output col/thread, r7's exact proven schedule (92% pipe
// fill) with the LDS layout halved: stage float4{a0,b0,a1,b1} per px PAIR
// (8 B/px -> 33.5 KB) and read each 12-px window as 6 aligned b128 (was
// 11). The tap-alignment parity problem (r8's killer) is solved by WAVE
// mapping: waves 0-3 own even cols, waves 4-7 odd cols (col = 2*(t&255) +
// (t>=256)) -> parity is wave-uniform and the 12 alignment weights live
// in SGPRs (readfirstlane-forced, s_cselect once; zero VGPR cost, nothing
// to rematerialize). q=a^2+b^2, p=ab recomputed at read (+2 ops/px).
// Carried, each HW-proven: 44-named-scalar ring (r3/r7: spill fix),
// 4-row dbuf chunks + ONE barrier/chunk (r6: barriers are live-range
// fences), launch_bounds (512,2) ONLY (r4/r9: tighter caps -> wholesale
// spill, 2x reproduced), staging split 2 rows/thread (coalesced).
__global__ void __launch_bounds__(512, 2) ssim_main_kernel(
    const float* __restrict__ img1, const float* __restrict__ img2,
    double* __restrict__ accum) {
  constexpr float GA[KS] = {
      0.00102838f, 0.00759884f, 0.03600087f, 0.10936069f, 0.21300553f,
      0.26601172f, 0.21300553f, 0.10936069f, 0.03600087f, 0.00759884f,
      0.00102838f};
  const float C1v = 1e-4f, C2v = 9e-4f;

  const int t  = threadIdx.x;          // 0..511
  const int r0 = blockIdx.x * TH;      // first output row of strip
  const int b  = blockIdx.y;           // batch index

  const float2* __restrict__ pp1 =
      reinterpret_cast<const float2*>(img1 + (size_t)b * HH * WW);
  const float2* __restrict__ pp2 =
      reinterpret_cast<const float2*>(img2 + (size_t)b * HH * WW);

  // Slot s holds px pair (2(s-3), 2(s-3)+1) as {a0,b0,a1,b1}.
  __shared__ float4 s4[2][4][NF4];
  __shared__ float wsum[8];

  // Zero horizontal pads of both buffers once (slots 0..2 and 259..261).
  if (t < 6) {
    const int idx = (t < 3) ? t : (256 + t);
#pragma unroll
    for (int bi = 0; bi < 2; ++bi)
#pragma unroll
      for (int r = 0; r < 4; ++r) s4[bi][r][idx] = make_float4(0.f, 0.f, 0.f, 0.f);
  }

  const int pi = t & 255;              // pair index (stage + window base)
  const int jA = (t >> 8) & 1;         // stage rows jA, jA+2; also col parity
  const int jB = jA + 2;
  const int base = pi + jA;            // first b128 slot of the 12-px window

  // Wave-uniform parity -> SGPR weights. Window px = pair-aligned 12 px
  // starting at col-6 (even) / col-5 (odd); read kk covers px (v.x,v.y)
  // = pair lo, (v.z,v.w) = pair hi. Tap weights:
  //   even: x-> {0,G1,G3,G5,G7,G9},  z-> {G0,G2,G4,G6,G8,G10}
  //   odd : x-> {G0,G2,G4,G6,G8,G10}, z-> {G1,G3,G5,G7,G9,0}
#define RFL(x) __int_as_float(__builtin_amdgcn_readfirstlane(__float_as_int(x)))
  const bool oddp = ((__builtin_amdgcn_readfirstlane(t) >> 8) & 1) != 0;
  const float wx0 = RFL(oddp ? GA[0]  : 0.f);
  const float wx1 = RFL(oddp ? GA[2]  : GA[1]);
  const float wx2 = RFL(oddp ? GA[4]  : GA[3]);
  const float wx3 = RFL(oddp ? GA[6]  : GA[5]);
  const float wx4 = RFL(oddp ? GA[8]  : GA[7]);
  const float wx5 = RFL(oddp ? GA[10] : GA[9]);
  const float wz0 = RFL(oddp ? GA[1]  : GA[0]);
  const float wz1 = RFL(oddp ? GA[3]  : GA[2]);
  const float wz2 = RFL(oddp ? GA[5]  : GA[4]);
  const float wz3 = RFL(oddp ? GA[7]  : GA[6]);
  const float wz4 = RFL(oddp ? GA[9]  : GA[8]);
  const float wz5 = RFL(oddp ? 0.f    : GA[10]);

  // Ring: 44 named scalars; slot s holds h-conv of input row rc, rc%11==s.
#define DECLR(s) float zA##s = 0.f, zB##s = 0.f, zQ##s = 0.f, zP##s = 0.f;
  DECLR(0) DECLR(1) DECLR(2) DECLR(3) DECLR(4) DECLR(5)
  DECLR(6) DECLR(7) DECLR(8) DECLR(9) DECLR(10)

  float2 taA, tbA, taB, tbB;           // staging regs (2 rows/thread)
  float local = 0.f;

  // Load the two staged rows of chunk k_ (rows jA and jB=jA+2); row
  // validity uniform per half-block; jB row of chunk 10 folds away.
#define LOADC(k_) {                                                     \
    taA = make_float2(0.f, 0.f); tbA = make_float2(0.f, 0.f);           \
    taB = make_float2(0.f, 0.f); tbB = make_float2(0.f, 0.f);           \
    { const int rr_ = r0 - PADK + 4 * (k_) + jA;                        \
      if ((unsigned)rr_ < HH) { const int o_ = rr_ * (WW / 2) + pi;     \
        taA = pp1[o_]; tbA = pp2[o_]; } }                               \
    if (4 * (k_) + jB < NIN) {                                          \
      const int rr_ = r0 - PADK + 4 * (k_) + jB;                        \
      if ((unsigned)rr_ < HH) { const int o_ = rr_ * (WW / 2) + pi;     \
        taB = pp1[o_]; tbB = pp2[o_]; } } }

  // Stage chunk k_ into buffer k_&1: one packed b128 per staged row.
#define WRITEC(k_) {                                                    \
    s4[(k_) & 1][jA][pi + 3] = make_float4(taA.x, tbA.x, taA.y, tbA.y); \
    if (4 * (k_) + jB < NIN)                                            \
      s4[(k_) & 1][jB][pi + 3] =                                        \
          make_float4(taB.x, tbB.x, taB.y, tbB.y); }

  // One b128 of the window: 2 px, recompute q,p, 8 fma (weights = SGPR).
#define HK(bb_, j_, kk_, wx_, wz_) {                                    \
    const float4 v = s4[bb_][j_][base + kk_];                           \
    const float qx_ = fmaf(v.x, v.x, v.y * v.y);                        \
    const float px_ = v.x * v.y;                                        \
    h1 = fmaf(wx_, v.x, h1); h2 = fmaf(wx_, v.y, h2);                   \
    hq = fmaf(wx_, qx_, hq); hp = fmaf(wx_, px_, hp);                   \
    const float qz_ = fmaf(v.z, v.z, v.w * v.w);                        \
    const float pz_ = v.z * v.w;                                        \
    h1 = fmaf(wz_, v.z, h1); h2 = fmaf(wz_, v.w, h2);                   \
    hq = fmaf(wz_, qz_, hq); hp = fmaf(wz_, pz_, hp); }

  // Horizontal conv of LDS row j_ of buffer bb_ -> ring slot S. 6 b128.
#define HBODY(bb_, j_, S) {                                             \
    float h1 = 0.f, h2 = 0.f, hq = 0.f, hp = 0.f;                       \
    HK(bb_, j_, 0, wx0, wz0) HK(bb_, j_, 1, wx1, wz1)                   \
    HK(bb_, j_, 2, wx2, wz2) HK(bb_, j_, 3, wx3, wz3)                   \
    HK(bb_, j_, 4, wx4, wz4) HK(bb_, j_, 5, wx5, wz5)                   \
    zA##S = h1; zB##S = h2; zQ##S = hq; zP##S = hp; }

  // Vertical conv: explicit rotation, slot names literal. (r7 verbatim.)
#define VC(P, s0,s1,s2v,s3,s4v,s5,s6v,s7,s8,s9,s10)                     \
  fmaf(GA[10], P##s10, fmaf(GA[9], P##s9, fmaf(GA[8], P##s8,            \
  fmaf(GA[7], P##s7, fmaf(GA[6], P##s6v, fmaf(GA[5], P##s5,             \
  fmaf(GA[4], P##s4v, fmaf(GA[3], P##s3, fmaf(GA[2], P##s2v,            \
  fmaf(GA[1], P##s1, GA[0] * P##s0))))))))))

#define VOUTBODY(s0,s1,s2v,s3,s4v,s5,s6v,s7,s8,s9,s10)                  \
  {                                                                     \
    const float m1 = VC(zA, s0,s1,s2v,s3,s4v,s5,s6v,s7,s8,s9,s10);      \
    const float m2 = VC(zB, s0,s1,s2v,s3,s4v,s5,s6v,s7,s8,s9,s10);      \
    const float mq = VC(zQ, s0,s1,s2v,s3,s4v,s5,s6v,s7,s8,s9,s10);      \
    const float mp = VC(zP, s0,s1,s2v,s3,s4v,s5,s6v,s7,s8,s9,s10);      \
    const float m1s = m1 * m1, m2s = m2 * m2, m12 = m1 * m2;            \
    const float s12 = mp - m12;                                         \
    const float sqq = mq - m1s - m2s;                                   \
    const float num = fmaf(2.f, m12, C1v) * fmaf(2.f, s12, C2v);        \
    const float den = (m1s + m2s + C1v) * (sqq + C2v);                  \
    local = fmaf(num, __builtin_amdgcn_rcpf(den), local);               \
  }

#define ROT0  0,1,2,3,4,5,6,7,8,9,10
#define ROT1  1,2,3,4,5,6,7,8,9,10,0
#define ROT2  2,3,4,5,6,7,8,9,10,0,1
#define ROT3  3,4,5,6,7,8,9,10,0,1,2
#define ROT4  4,5,6,7,8,9,10,0,1,2,3
#define ROT5  5,6,7,8,9,10,0,1,2,3,4
#define ROT6  6,7,8,9,10,0,1,2,3,4,5
#define ROT7  7,8,9,10,0,1,2,3,4,5,6
#define ROT8  8,9,10,0,1,2,3,4,5,6,7
#define ROT9  9,10,0,1,2,3,4,5,6,7,8
#define ROT10 10,0,1,2,3,4,5,6,7,8,9
#define VOUTE(...) VOUTBODY(__VA_ARGS__)

#define ROWH(bb_, j_, S)      { HBODY(bb_, j_, S) }
#define ROWO(bb_, j_, S, R_)  { HBODY(bb_, j_, S) VOUTE(R_) }

  // Prologue: prefetch chunk 0.
  LOADC(0)

  // Per chunk ii (buf = ii&1): write staged regs; ONE barrier; prefetch
  // chunk ii+1; compute the 4 rows. rc = 4*ii+j; ring slot S = rc%11;
  // output row rc-10 emitted when rc >= 10, rotation start (rc+1)%11.
  // (Schedule identical to r7 — proven 92% pipe fill.)
  // ii=0: rc 0-3
  WRITEC(0) __syncthreads(); LOADC(1)
  ROWH(0,0,0) ROWH(0,1,1) ROWH(0,2,2) ROWH(0,3,3)
  // ii=1: rc 4-7
  WRITEC(1) __syncthreads(); LOADC(2)
  ROWH(1,0,4) ROWH(1,1,5) ROWH(1,2,6) ROWH(1,3,7)
  // ii=2: rc 8-11 (rc10,11 -> output rows 0,1)
  WRITEC(2) __syncthreads(); LOADC(3)
  ROWH(0,0,8) ROWH(0,1,9)
  ROWO(0,2,10, ROT0) ROWO(0,3,0, ROT1)
  // ii=3: rc 12-15
  WRITEC(3) __syncthreads(); LOADC(4)
  ROWO(1,0,1, ROT2) ROWO(1,1,2, ROT3) ROWO(1,2,3, ROT4) ROWO(1,3,4, ROT5)
  // ii=4: rc 16-19
  WRITEC(4) __syncthreads(); LOADC(5)
  ROWO(0,0,5, ROT6) ROWO(0,1,6, ROT7) ROWO(0,2,7, ROT8) ROWO(0,3,8, ROT9)
  // ii=5: rc 20-23
  WRITEC(5) __syncthreads(); LOADC(6)
  ROWO(1,0,9, ROT10) ROWO(1,1,10, ROT0) ROWO(1,2,0, ROT1) ROWO(1,3,1, ROT2)
  // ii=6: rc 24-27
  WRITEC(6) __syncthreads(); LOADC(7)
  ROWO(0,0,2, ROT3) ROWO(0,1,3, ROT4) ROWO(0,2,4, ROT5) ROWO(0,3,5, ROT6)
  // ii=7: rc 28-31
  WRITEC(7) __syncthreads(); LOADC(8)
  ROWO(1,0,6, ROT7) ROWO(1,1,7, ROT8) ROWO(1,2,8, ROT9) ROWO(1,3,9, ROT10)
  // ii=8: rc 32-35
  WRITEC(8) __syncthreads(); LOADC(9)
  ROWO(0,0,10, ROT0) ROWO(0,1,0, ROT1) ROWO(0,2,1, ROT2) ROWO(0,3,2, ROT3)
  // ii=9: rc 36-39
  WRITEC(9) __syncthreads(); LOADC(10)
  ROWO(1,0,3, ROT4) ROWO(1,1,4, ROT5) ROWO(1,2,5, ROT6) ROWO(1,3,6, ROT7)
  // ii=10: rc 40,41 (output rows 30,31; rows 42,43 guarded off)
  WRITEC(10) __syncthreads();
  ROWO(0,0,7, ROT8) ROWO(0,1,8, ROT9)

  // Block reduction: wave64 shuffle -> LDS -> one double atomic per block.
#pragma unroll
  for (int off = 32; off > 0; off >>= 1) local += __shfl_down(local, off, 64);
  const int wave = t >> 6;
  const int lane = t & 63;
  if (lane == 0) wsum[wave] = local;
  __syncthreads();
  if (t == 0) {
    float s = 0.f;
#pragma unroll
    for (int w = 0; w < 8; ++w) s += wsum[w];
    atomicAdd(accum, (double)s);
  }
}

__global__ void ssim_final_kernel(const double* __restrict__ accum,
                                  float* __restrict__ out) {
  out[0] = 1.0f - (float)(accum[0] / NPIX);
}

extern "C" void kernel_launch(void* const* d_in, const int* in_sizes, int n_in,
                              void* d_out, int out_size, void* d_ws, size_t ws_size,
                              hipStream_t stream) {
  const float* img1 = (const float*)d_in[0];
  const float* img2 = (const float*)d_in[1];
  double* accum = (double*)d_ws;
  hipMemsetAsync(accum, 0, sizeof(double), stream);

  dim3 grid(HH / TH, BATCH);
  ssim_main_kernel<<<grid, 512, 0, stream>>>(img1, img2, accum);
  ssim_final_kernel<<<1, 1, 0, stream>>>(accum, (float*)d_out);
}